// Round 6
// baseline (823.853 us; speedup 1.0000x reference)
//
#include <hip/hip_runtime.h>

typedef unsigned short u16;
typedef __attribute__((ext_vector_type(8))) short short8;
typedef __attribute__((ext_vector_type(4))) float float4v;

#define HID 64
#define MOLD 9
#define BSH 10           // bucket covers 1<<BSH = 1024 nodes
#define NBM 256          // max buckets (N <= 262144; src packs in 18 bits)
#define NBLK 256         // partition blocks

__device__ __forceinline__ float bf2f(u16 u) {
    return __uint_as_float(((unsigned)u) << 16);
}
__device__ __forceinline__ u16 f2bf(float f) {
    unsigned x = __float_as_uint(f);
    unsigned r = (x + 0x7FFFu + ((x >> 16) & 1u)) >> 16;  // round-nearest-even
    return (u16)r;
}
__device__ __forceinline__ void unpack_add(uint4 r, float* a) {
    a[0] += __uint_as_float(r.x << 16); a[1] += __uint_as_float(r.x & 0xffff0000u);
    a[2] += __uint_as_float(r.y << 16); a[3] += __uint_as_float(r.y & 0xffff0000u);
    a[4] += __uint_as_float(r.z << 16); a[5] += __uint_as_float(r.z & 0xffff0000u);
    a[6] += __uint_as_float(r.w << 16); a[7] += __uint_as_float(r.w & 0xffff0000u);
}
__device__ __forceinline__ void unpack_set(uint4 r, float* a) {
    a[0] = __uint_as_float(r.x << 16); a[1] = __uint_as_float(r.x & 0xffff0000u);
    a[2] = __uint_as_float(r.y << 16); a[3] = __uint_as_float(r.y & 0xffff0000u);
    a[4] = __uint_as_float(r.z << 16); a[5] = __uint_as_float(r.z & 0xffff0000u);
    a[6] = __uint_as_float(r.w << 16); a[7] = __uint_as_float(r.w & 0xffff0000u);
}

// ---- dtype probe ----
__global__ void k_detect(const u16* __restrict__ p, int n, int* __restrict__ flag) {
    bool bad = false;
    for (int i = threadIdx.x; i < n; i += 256) {
        float v = bf2f(p[i]);
        if (!(v == v) || fabsf(v) > 1000.f) bad = true;
    }
    if (bad) atomicOr(flag, 1);
}

__device__ __forceinline__ void cvt_seg(const void* src, u16* dst, int n, int mode) {
    if (mode) {
        const float* s = (const float*)src;
        for (int i = threadIdx.x; i < n; i += 256) dst[i] = f2bf(s[i]);
    } else {
        const u16* s = (const u16*)src;
        for (int i = threadIdx.x; i < n; i += 256) dst[i] = s[i];
    }
}

__global__ void k_cvt_w(const void* W1, const void* b1, const void* W2, const void* b2,
                        const void* W3, const void* b3, const void* Wl, const void* bl,
                        const int* __restrict__ flag, u16* __restrict__ wbf) {
    int mode = *flag;
    cvt_seg(W1, wbf + 0,     MOLD * HID, mode);
    cvt_seg(b1, wbf + 576,   HID, mode);
    cvt_seg(W2, wbf + 640,   HID * HID, mode);
    cvt_seg(b2, wbf + 4736,  HID, mode);
    cvt_seg(W3, wbf + 4800,  HID * HID, mode);
    cvt_seg(b3, wbf + 8896,  HID, mode);
    cvt_seg(Wl, wbf + 8960,  2 * HID * HID, mode);
    cvt_seg(bl, wbf + 17152, HID, mode);
}

__global__ void k_cvt_x(const void* __restrict__ src, u16* __restrict__ dst, int n,
                        const int* __restrict__ flag) {
    int mode = *flag;
    int i = blockIdx.x * 256 + threadIdx.x;
    if (i >= n) return;
    dst[i] = mode ? f2bf(((const float*)src)[i]) : ((const u16*)src)[i];
}

// ==== atomic-free two-level radix CSR build ====
__global__ __launch_bounds__(256) void k_hist(const int* __restrict__ ei, int E, int nb,
                                              int chunk, int* __restrict__ cntmat) {
    __shared__ int h[NBM];
    int tid = threadIdx.x, k = blockIdx.x;
    for (int i = tid; i < nb; i += 256) h[i] = 0;
    __syncthreads();
    int e0 = k * chunk, e1 = e0 + chunk; if (e1 > E) e1 = E;
    for (int e = e0 + tid; e < e1; e += 256)
        atomicAdd(&h[ei[E + e] >> BSH], 1);
    __syncthreads();
    for (int b = tid; b < nb; b += 256) cntmat[b * NBLK + k] = h[b];
}

__global__ __launch_bounds__(1024) void k_scanmat(int* __restrict__ cntmat, int total) {
    __shared__ int ps[1024];
    int tid = threadIdx.x;
    int chunk = (total + 1023) >> 10;
    int i0 = tid * chunk, i1 = i0 + chunk; if (i1 > total) i1 = total;
    int sum = 0;
    for (int i = i0; i < i1; i++) sum += cntmat[i];
    ps[tid] = sum;
    __syncthreads();
    for (int off = 1; off < 1024; off <<= 1) {
        int t = (tid >= off) ? ps[tid - off] : 0;
        __syncthreads();
        ps[tid] += t;
        __syncthreads();
    }
    int run = ps[tid] - sum;
    for (int i = i0; i < i1; i++) { int c = cntmat[i]; cntmat[i] = run; run += c; }
}

__global__ __launch_bounds__(256) void k_scatter(const int* __restrict__ ei, int E, int nb,
                                                 int chunk, const int* __restrict__ offmat,
                                                 unsigned* __restrict__ staging) {
    __shared__ int cur[NBM];
    int tid = threadIdx.x, k = blockIdx.x;
    for (int b = tid; b < nb; b += 256) cur[b] = offmat[b * NBLK + k];
    __syncthreads();
    int e0 = k * chunk, e1 = e0 + chunk; if (e1 > E) e1 = E;
    for (int e = e0 + tid; e < e1; e += 256) {
        int s = ei[e];
        int d = ei[E + e];
        int b = d >> BSH;
        int p = atomicAdd(&cur[b], 1);
        staging[p] = (unsigned)s | ((unsigned)(d & ((1 << BSH) - 1)) << 18);
    }
}

__global__ __launch_bounds__(256) void k_p4(const unsigned* __restrict__ staging,
                                            const int* __restrict__ offmat, int nb, int N, int E,
                                            int* __restrict__ col, int* __restrict__ rowptr,
                                            float* __restrict__ dinv) {
    __shared__ int cnt[1 << BSH];
    __shared__ int cur[1 << BSH];
    __shared__ int ps[256];
    int b = blockIdx.x, tid = threadIdx.x;
    int s0 = offmat[b * NBLK];
    int s1 = (b == nb - 1) ? E : offmat[(b + 1) * NBLK];
    for (int i = tid; i < (1 << BSH); i += 256) cnt[i] = 0;
    __syncthreads();
    for (int i = s0 + tid; i < s1; i += 256)
        atomicAdd(&cnt[staging[i] >> 18], 1);
    __syncthreads();
    int base4 = tid * 4;
    int c0 = cnt[base4], c1 = cnt[base4 + 1], c2 = cnt[base4 + 2], c3 = cnt[base4 + 3];
    int tsum = c0 + c1 + c2 + c3;
    ps[tid] = tsum;
    __syncthreads();
    for (int off = 1; off < 256; off <<= 1) {
        int t = (tid >= off) ? ps[tid - off] : 0;
        __syncthreads();
        ps[tid] += t;
        __syncthreads();
    }
    int ex = ps[tid] - tsum;
    int o0 = s0 + ex, o1 = o0 + c0, o2 = o1 + c1, o3 = o2 + c2;
    cur[base4] = o0; cur[base4 + 1] = o1; cur[base4 + 2] = o2; cur[base4 + 3] = o3;
    int v = (b << BSH) + base4;
    if (v < N)     { rowptr[v] = o0;     dinv[v] = rsqrtf((float)(c0 + 1)); }
    if (v + 1 < N) { rowptr[v + 1] = o1; dinv[v + 1] = rsqrtf((float)(c1 + 1)); }
    if (v + 2 < N) { rowptr[v + 2] = o2; dinv[v + 2] = rsqrtf((float)(c2 + 1)); }
    if (v + 3 < N) { rowptr[v + 3] = o3; dinv[v + 3] = rsqrtf((float)(c3 + 1)); }
    if (b == nb - 1 && tid == 0) rowptr[N] = E;
    __syncthreads();
    for (int i = s0 + tid; i < s1; i += 256) {
        unsigned w = staging[i];
        int p = atomicAdd(&cur[w >> 18], 1);
        col[p] = (int)(w & 0x3FFFF);
    }
}

// ---- layer-1 dense ----
__global__ void k_l1(const u16* __restrict__ x, const u16* __restrict__ wseg,
                     const float* __restrict__ dinv, int N, u16* __restrict__ y) {
    __shared__ float w[MOLD * HID];
    int tid = threadIdx.x;
    for (int i = tid; i < MOLD * HID; i += blockDim.x) w[i] = bf2f(wseg[i]);
    __syncthreads();
    int v = blockIdx.x * 4 + (tid >> 6);
    int f = tid & 63;
    if (v >= N) return;
    float acc = 0.f;
#pragma unroll
    for (int k = 0; k < MOLD; k++) acc += bf2f(x[v * MOLD + k]) * w[k * HID + f];
    y[v * HID + f] = f2bf(dinv[v] * acc);
}

__device__ __forceinline__ void load_bias(const u16* bseg, int fg, float* breg) {
    uint4 bv = ((const uint4*)bseg)[fg];
    unpack_set(bv, breg);
}

// ---- dual-node gather: two independent load chains in flight per wave ----
// Computes post-relu hA[8], hB[8] (feats fg*8+j), valid on ALL lanes.
__device__ __forceinline__ void gather_pair(const u16* __restrict__ y,
                                            const int* __restrict__ rowptr,
                                            const int* __restrict__ col,
                                            float dvA, float dvB, const float* breg,
                                            int vA, int vB, bool hasB,
                                            int eslot, int fg, float* hA, float* hB) {
    float accA[8], accB[8];
    const u16* yf = y + fg * 8;   // lane-constant feature offset
    if (eslot == 0) {
        unpack_set(*(const uint4*)(yf + (size_t)vA * HID), accA);
    } else {
#pragma unroll
        for (int j = 0; j < 8; j++) accA[j] = 0.f;
    }
    if (hasB && eslot == 0) {
        unpack_set(*(const uint4*)(yf + (size_t)vB * HID), accB);
    } else {
#pragma unroll
        for (int j = 0; j < 8; j++) accB[j] = 0.f;
    }
    int eA = rowptr[vA + 1];
    int iA = rowptr[vA] + eslot;
    int iB, eB;
    if (hasB) { iB = eA + eslot; eB = rowptr[vB + 1]; }  // rowptr[vB] == eA (CSR)
    else      { iB = 0; eB = 0; }
    while (iA < eA || iB < eB) {
        bool hA_ = iA < eA, hB_ = iB < eB;
        int uA = 0, uB = 0;
        if (hA_) uA = col[iA];
        if (hB_) uB = col[iB];
        uint4 rA, rB;
        if (hA_) rA = *(const uint4*)(yf + (size_t)uA * HID);
        if (hB_) rB = *(const uint4*)(yf + (size_t)uB * HID);
        if (hA_) unpack_add(rA, accA);
        if (hB_) unpack_add(rB, accB);
        iA += 8; iB += 8;
    }
#pragma unroll
    for (int j = 0; j < 8; j++) { accA[j] += __shfl_xor(accA[j], 8);  accB[j] += __shfl_xor(accB[j], 8); }
#pragma unroll
    for (int j = 0; j < 8; j++) { accA[j] += __shfl_xor(accA[j], 16); accB[j] += __shfl_xor(accB[j], 16); }
#pragma unroll
    for (int j = 0; j < 8; j++) { accA[j] += __shfl_xor(accA[j], 32); accB[j] += __shfl_xor(accB[j], 32); }
#pragma unroll
    for (int j = 0; j < 8; j++) {
        hA[j] = fmaxf(dvA * accA[j] + breg[j], 0.f);
        hB[j] = fmaxf(dvB * accB[j] + breg[j], 0.f);
    }
}

__device__ __forceinline__ void store_row(u16* __restrict__ h, int v, int fg, const float* hj) {
    uint4 o;
    o.x = (unsigned)f2bf(hj[0]) | ((unsigned)f2bf(hj[1]) << 16);
    o.y = (unsigned)f2bf(hj[2]) | ((unsigned)f2bf(hj[3]) << 16);
    o.z = (unsigned)f2bf(hj[4]) | ((unsigned)f2bf(hj[5]) << 16);
    o.w = (unsigned)f2bf(hj[6]) | ((unsigned)f2bf(hj[7]) << 16);
    ((uint4*)(h + (size_t)v * HID))[fg] = o;
}

// ---- agg layers 1,2 (dual-node) ----
__global__ __launch_bounds__(256, 4) void k_agg(
        const u16* __restrict__ y, const int* __restrict__ rowptr,
        const int* __restrict__ col, const float* __restrict__ dinv,
        const u16* __restrict__ bseg, int N, u16* __restrict__ h) {
    int lane = threadIdx.x & 63;
    int eslot = lane >> 3, fg = lane & 7;
    int wid = (blockIdx.x * blockDim.x + threadIdx.x) >> 6;
    int nw = (gridDim.x * blockDim.x) >> 6;
    float breg[8];
    load_bias(bseg, fg, breg);
    int cpw = ((N + nw - 1) / nw + 1) & ~1;   // even chunk per wave
    int v0 = wid * cpw;
    int v1 = v0 + cpw; if (v1 > N) v1 = N;
    for (int v = v0; v < v1; v += 2) {
        bool hasB = (v + 1 < v1);
        float hjA[8], hjB[8];
        gather_pair(y, rowptr, col, dinv[v], hasB ? dinv[v + 1] : 0.f, breg,
                    v, v + 1, hasB, eslot, fg, hjA, hjB);
        if (eslot == 0) {
            store_row(h, v, fg, hjA);
            if (hasB) store_row(h, v + 1, fg, hjB);
        }
    }
}

// ---- agg layer 3 + fused pooling (dual-node) ----
__global__ __launch_bounds__(256, 4) void k_aggpool(
        const u16* __restrict__ y, const int* __restrict__ rowptr,
        const int* __restrict__ col, const float* __restrict__ dinv,
        const u16* __restrict__ bseg, const int* __restrict__ batch, int N,
        float* __restrict__ hsum, int* __restrict__ hmax, int* __restrict__ cnt) {
    int lane = threadIdx.x & 63;
    int eslot = lane >> 3, fg = lane & 7;
    int wid = (blockIdx.x * blockDim.x + threadIdx.x) >> 6;
    int nw = (gridDim.x * blockDim.x) >> 6;
    float breg[8];
    load_bias(bseg, fg, breg);
    int cpw = ((N + nw - 1) / nw + 1) & ~1;
    int v0 = wid * cpw;
    int v1 = v0 + cpw; if (v1 > N) v1 = N;
    int gcur = -1, pcnt = 0;
    float psum[8], pmax[8];
#pragma unroll
    for (int j = 0; j < 8; j++) { psum[j] = 0.f; pmax[j] = 0.f; }
    for (int v = v0; v < v1; v += 2) {
        bool hasB = (v + 1 < v1);
        float hjA[8], hjB[8];
        gather_pair(y, rowptr, col, dinv[v], hasB ? dinv[v + 1] : 0.f, breg,
                    v, v + 1, hasB, eslot, fg, hjA, hjB);
        for (int t = 0; t < (hasB ? 2 : 1); ++t) {
            const float* hj = t ? hjB : hjA;
            int g = batch[v + t];
            if (g != gcur) {
                if (gcur >= 0) {
                    if (eslot == 0) {
#pragma unroll
                        for (int j = 0; j < 8; j++) {
                            atomicAdd(&hsum[gcur * HID + fg * 8 + j], psum[j]);
                            atomicMax(&hmax[gcur * HID + fg * 8 + j], __float_as_int(pmax[j]));
                        }
                    }
                    if (lane == 0) atomicAdd(&cnt[gcur], pcnt);
                }
#pragma unroll
                for (int j = 0; j < 8; j++) { psum[j] = 0.f; pmax[j] = 0.f; }
                pcnt = 0;
                gcur = g;
            }
            pcnt++;
#pragma unroll
            for (int j = 0; j < 8; j++) {
                psum[j] += hj[j];
                pmax[j] = fmaxf(pmax[j], hj[j]);
            }
        }
    }
    if (gcur >= 0) {
        if (eslot == 0) {
#pragma unroll
            for (int j = 0; j < 8; j++) {
                atomicAdd(&hsum[gcur * HID + fg * 8 + j], psum[j]);
                atomicMax(&hmax[gcur * HID + fg * 8 + j], __float_as_int(pmax[j]));
            }
        }
        if (lane == 0) atomicAdd(&cnt[gcur], pcnt);
    }
}

// ---- MFMA 64x64 dense ----
__global__ __launch_bounds__(256, 4) void k_mm(
        const u16* __restrict__ h, const u16* __restrict__ W,
        const float* __restrict__ dinv, int N, u16* __restrict__ y) {
    int lane = threadIdx.x & 63;
    int q = lane >> 4, m = lane & 15;
    int wid = (blockIdx.x * blockDim.x + threadIdx.x) >> 6;
    int nw = (gridDim.x * blockDim.x) >> 6;
    short8 bfrag[4][2];
#pragma unroll
    for (int t = 0; t < 4; ++t)
#pragma unroll
        for (int kh = 0; kh < 2; ++kh) {
            short8 bv;
#pragma unroll
            for (int j = 0; j < 8; ++j)
                bv[j] = (short)W[(kh * 32 + q * 8 + j) * HID + t * 16 + m];
            bfrag[t][kh] = bv;
        }
    const float4v zero = {0.f, 0.f, 0.f, 0.f};
    int ntiles = (N + 15) >> 4;
    for (int tile = wid; tile < ntiles; tile += nw) {
        int base = tile * 16;
        int row = base + m;
        short8 a0 = {0, 0, 0, 0, 0, 0, 0, 0}, a1 = a0;
        if (row < N) {
            uint4 r0 = *(const uint4*)(h + (size_t)row * HID + q * 8);
            uint4 r1 = *(const uint4*)(h + (size_t)row * HID + 32 + q * 8);
            a0 = __builtin_bit_cast(short8, r0);
            a1 = __builtin_bit_cast(short8, r1);
        }
        float4v c[4];
#pragma unroll
        for (int t = 0; t < 4; ++t) c[t] = zero;
#pragma unroll
        for (int t = 0; t < 4; ++t) {
            c[t] = __builtin_amdgcn_mfma_f32_16x16x32_bf16(a0, bfrag[t][0], c[t], 0, 0, 0);
            c[t] = __builtin_amdgcn_mfma_f32_16x16x32_bf16(a1, bfrag[t][1], c[t], 0, 0, 0);
        }
#pragma unroll
        for (int r = 0; r < 4; ++r) {
            int node = base + q * 4 + r;
            if (node < N) {
                float dv = dinv[node];
#pragma unroll
                for (int t = 0; t < 4; ++t)
                    y[(size_t)node * HID + t * 16 + m] = f2bf(c[t][r] * dv);
            }
        }
    }
}

// ---- final linear ----
__global__ void k_final(const float* __restrict__ hsum, const int* __restrict__ hmaxi,
                        const int* __restrict__ cnt, const u16* __restrict__ wlseg,
                        const u16* __restrict__ blseg, const int* __restrict__ flag,
                        int G, void* __restrict__ out) {
    __shared__ float w[2 * HID * HID];
    int tid = threadIdx.x;
    for (int i = tid; i < 2 * HID * HID; i += blockDim.x) w[i] = bf2f(wlseg[i]);
    __syncthreads();
    int g = blockIdx.x * 4 + (tid >> 6);
    int f = tid & 63;
    if (g >= G) return;
    float inv = 1.f / fmaxf((float)cnt[g], 1.f);
    float acc = bf2f(blseg[f]);
#pragma unroll 8
    for (int k = 0; k < HID; k++) acc += (hsum[g * HID + k] * inv) * w[k * HID + f];
#pragma unroll 8
    for (int k = 0; k < HID; k++) acc += __int_as_float(hmaxi[g * HID + k]) * w[(HID + k) * HID + f];
    int mode = *flag;
    if (mode) ((float*)out)[g * HID + f] = acc;
    else      ((u16*)out)[g * HID + f] = f2bf(acc);
}

extern "C" void kernel_launch(void* const* d_in, const int* in_sizes, int n_in,
                              void* d_out, int out_size, void* d_ws, size_t ws_size,
                              hipStream_t stream) {
    const void* x  = d_in[0];
    const int*  ei = (const int*)d_in[1];
    const int*  batch = (const int*)d_in[3];

    const int NX = in_sizes[0];
    const int N  = NX / MOLD;
    const int E  = in_sizes[1] / 2;
    const int G  = out_size / HID;
    const int nb = (N + (1 << BSH) - 1) >> BSH;

    char* p = (char*)d_ws;
    auto alloc = [&](size_t bytes) -> char* {
        char* r = p;
        p += (bytes + 255) & ~(size_t)255;
        return r;
    };
    int*   flag    = (int*)alloc(256);
    int*   rowptr  = (int*)alloc((size_t)(N + 1) * 4);
    float* dinv    = (float*)alloc((size_t)N * 4);
    int*   cntmat  = (int*)alloc((size_t)nb * NBLK * 4);
    u16*   wbf     = (u16*)alloc((size_t)17216 * 2);
    int*   colb    = (int*)alloc((size_t)E * 4);
    size_t hb = (size_t)N * HID * 2;
    size_t sb = (size_t)E * 4;
    size_t xb = (size_t)NX * 2;
    size_t ub = hb > sb ? hb : sb; if (xb > ub) ub = xb;
    char* hbuf = alloc(ub);
    unsigned* staging = (unsigned*)hbuf;
    u16*      xbf     = (u16*)hbuf;
    u16*      hbf     = (u16*)hbuf;
    u16*   ybf  = (u16*)alloc((size_t)N * HID * 2);
    float* hsum = (float*)alloc((size_t)G * HID * 4);
    int*   hmax = (int*)alloc((size_t)G * HID * 4);
    int*   cnt  = (int*)alloc((size_t)G * 4);

    hipMemsetAsync(flag, 0, 256, stream);
    hipMemsetAsync(hsum, 0, (size_t)G * HID * 4, stream);
    hipMemsetAsync(hmax, 0, (size_t)G * HID * 4, stream);
    hipMemsetAsync(cnt, 0, (size_t)G * 4, stream);

    k_detect<<<1, 256, 0, stream>>>((const u16*)x, 8192, flag);
    k_cvt_w<<<1, 256, 0, stream>>>(d_in[4], d_in[5], d_in[6], d_in[7],
                                   d_in[8], d_in[9], d_in[10], d_in[11], flag, wbf);

    int chunk = (E + NBLK - 1) / NBLK;
    k_hist<<<NBLK, 256, 0, stream>>>(ei, E, nb, chunk, cntmat);
    k_scanmat<<<1, 1024, 0, stream>>>(cntmat, nb * NBLK);
    k_scatter<<<NBLK, 256, 0, stream>>>(ei, E, nb, chunk, cntmat, staging);
    k_p4<<<nb, 256, 0, stream>>>(staging, cntmat, nb, N, E, colb, rowptr, dinv);

    k_cvt_x<<<(NX + 255) / 256, 256, 0, stream>>>(x, xbf, NX, flag);
    k_l1<<<(N + 3) / 4, 256, 0, stream>>>(xbf, wbf + 0, dinv, N, ybf);

    k_agg<<<2048, 256, 0, stream>>>(ybf, rowptr, colb, dinv, wbf + 576, N, hbf);
    k_mm<<<1024, 256, 0, stream>>>(hbf, wbf + 640, dinv, N, ybf);
    k_agg<<<2048, 256, 0, stream>>>(ybf, rowptr, colb, dinv, wbf + 4736, N, hbf);
    k_mm<<<1024, 256, 0, stream>>>(hbf, wbf + 4800, dinv, N, ybf);
    k_aggpool<<<2048, 256, 0, stream>>>(ybf, rowptr, colb, dinv, wbf + 8896, batch, N,
                                        hsum, hmax, cnt);

    k_final<<<(G + 3) / 4, 256, 0, stream>>>(hsum, hmax, cnt, wbf + 8960, wbf + 17152,
                                             flag, G, d_out);
}

// Round 7
// 702.141 us; speedup vs baseline: 1.1733x; 1.1733x over previous
//
#include <hip/hip_runtime.h>

typedef unsigned short u16;
typedef __attribute__((ext_vector_type(8))) short short8;
typedef __attribute__((ext_vector_type(4))) float float4v;

#define HID 64
#define MOLD 9
#define BSH 10           // bucket covers 1<<BSH = 1024 nodes
#define NBM 256          // max buckets (N <= 262144; src packs in 18 bits)
#define NBLK 256         // partition blocks

__device__ __forceinline__ float bf2f(u16 u) {
    return __uint_as_float(((unsigned)u) << 16);
}
__device__ __forceinline__ u16 f2bf(float f) {
    unsigned x = __float_as_uint(f);
    unsigned r = (x + 0x7FFFu + ((x >> 16) & 1u)) >> 16;  // round-nearest-even
    return (u16)r;
}
__device__ __forceinline__ void unpack_add(uint4 r, float* a) {
    a[0] += __uint_as_float(r.x << 16); a[1] += __uint_as_float(r.x & 0xffff0000u);
    a[2] += __uint_as_float(r.y << 16); a[3] += __uint_as_float(r.y & 0xffff0000u);
    a[4] += __uint_as_float(r.z << 16); a[5] += __uint_as_float(r.z & 0xffff0000u);
    a[6] += __uint_as_float(r.w << 16); a[7] += __uint_as_float(r.w & 0xffff0000u);
}
__device__ __forceinline__ void unpack_set(uint4 r, float* a) {
    a[0] = __uint_as_float(r.x << 16); a[1] = __uint_as_float(r.x & 0xffff0000u);
    a[2] = __uint_as_float(r.y << 16); a[3] = __uint_as_float(r.y & 0xffff0000u);
    a[4] = __uint_as_float(r.z << 16); a[5] = __uint_as_float(r.z & 0xffff0000u);
    a[6] = __uint_as_float(r.w << 16); a[7] = __uint_as_float(r.w & 0xffff0000u);
}

// ---- dtype probe ----
__global__ void k_detect(const u16* __restrict__ p, int n, int* __restrict__ flag) {
    bool bad = false;
    for (int i = threadIdx.x; i < n; i += 256) {
        float v = bf2f(p[i]);
        if (!(v == v) || fabsf(v) > 1000.f) bad = true;
    }
    if (bad) atomicOr(flag, 1);
}

__device__ __forceinline__ void cvt_seg(const void* src, u16* dst, int n, int mode) {
    if (mode) {
        const float* s = (const float*)src;
        for (int i = threadIdx.x; i < n; i += 256) dst[i] = f2bf(s[i]);
    } else {
        const u16* s = (const u16*)src;
        for (int i = threadIdx.x; i < n; i += 256) dst[i] = s[i];
    }
}

__global__ void k_cvt_w(const void* W1, const void* b1, const void* W2, const void* b2,
                        const void* W3, const void* b3, const void* Wl, const void* bl,
                        const int* __restrict__ flag, u16* __restrict__ wbf) {
    int mode = *flag;
    cvt_seg(W1, wbf + 0,     MOLD * HID, mode);
    cvt_seg(b1, wbf + 576,   HID, mode);
    cvt_seg(W2, wbf + 640,   HID * HID, mode);
    cvt_seg(b2, wbf + 4736,  HID, mode);
    cvt_seg(W3, wbf + 4800,  HID * HID, mode);
    cvt_seg(b3, wbf + 8896,  HID, mode);
    cvt_seg(Wl, wbf + 8960,  2 * HID * HID, mode);
    cvt_seg(bl, wbf + 17152, HID, mode);
}

__global__ void k_cvt_x(const void* __restrict__ src, u16* __restrict__ dst, int n,
                        const int* __restrict__ flag) {
    int mode = *flag;
    int i = blockIdx.x * 256 + threadIdx.x;
    if (i >= n) return;
    dst[i] = mode ? f2bf(((const float*)src)[i]) : ((const u16*)src)[i];
}

// ==== atomic-free two-level radix CSR build ====
__global__ __launch_bounds__(256) void k_hist(const int* __restrict__ ei, int E, int nb,
                                              int chunk, int* __restrict__ cntmat) {
    __shared__ int h[NBM];
    int tid = threadIdx.x, k = blockIdx.x;
    for (int i = tid; i < nb; i += 256) h[i] = 0;
    __syncthreads();
    int e0 = k * chunk, e1 = e0 + chunk; if (e1 > E) e1 = E;
    for (int e = e0 + tid; e < e1; e += 256)
        atomicAdd(&h[ei[E + e] >> BSH], 1);
    __syncthreads();
    for (int b = tid; b < nb; b += 256) cntmat[b * NBLK + k] = h[b];
}

__global__ __launch_bounds__(1024) void k_scanmat(int* __restrict__ cntmat, int total) {
    __shared__ int ps[1024];
    int tid = threadIdx.x;
    int chunk = (total + 1023) >> 10;
    int i0 = tid * chunk, i1 = i0 + chunk; if (i1 > total) i1 = total;
    int sum = 0;
    for (int i = i0; i < i1; i++) sum += cntmat[i];
    ps[tid] = sum;
    __syncthreads();
    for (int off = 1; off < 1024; off <<= 1) {
        int t = (tid >= off) ? ps[tid - off] : 0;
        __syncthreads();
        ps[tid] += t;
        __syncthreads();
    }
    int run = ps[tid] - sum;
    for (int i = i0; i < i1; i++) { int c = cntmat[i]; cntmat[i] = run; run += c; }
}

__global__ __launch_bounds__(256) void k_scatter(const int* __restrict__ ei, int E, int nb,
                                                 int chunk, const int* __restrict__ offmat,
                                                 unsigned* __restrict__ staging) {
    __shared__ int cur[NBM];
    int tid = threadIdx.x, k = blockIdx.x;
    for (int b = tid; b < nb; b += 256) cur[b] = offmat[b * NBLK + k];
    __syncthreads();
    int e0 = k * chunk, e1 = e0 + chunk; if (e1 > E) e1 = E;
    for (int e = e0 + tid; e < e1; e += 256) {
        int s = ei[e];
        int d = ei[E + e];
        int b = d >> BSH;
        int p = atomicAdd(&cur[b], 1);
        staging[p] = (unsigned)s | ((unsigned)(d & ((1 << BSH) - 1)) << 18);
    }
}

__global__ __launch_bounds__(256) void k_p4(const unsigned* __restrict__ staging,
                                            const int* __restrict__ offmat, int nb, int N, int E,
                                            int* __restrict__ col, int* __restrict__ rowptr,
                                            float* __restrict__ dinv) {
    __shared__ int cnt[1 << BSH];
    __shared__ int cur[1 << BSH];
    __shared__ int ps[256];
    int b = blockIdx.x, tid = threadIdx.x;
    int s0 = offmat[b * NBLK];
    int s1 = (b == nb - 1) ? E : offmat[(b + 1) * NBLK];
    for (int i = tid; i < (1 << BSH); i += 256) cnt[i] = 0;
    __syncthreads();
    for (int i = s0 + tid; i < s1; i += 256)
        atomicAdd(&cnt[staging[i] >> 18], 1);
    __syncthreads();
    int base4 = tid * 4;
    int c0 = cnt[base4], c1 = cnt[base4 + 1], c2 = cnt[base4 + 2], c3 = cnt[base4 + 3];
    int tsum = c0 + c1 + c2 + c3;
    ps[tid] = tsum;
    __syncthreads();
    for (int off = 1; off < 256; off <<= 1) {
        int t = (tid >= off) ? ps[tid - off] : 0;
        __syncthreads();
        ps[tid] += t;
        __syncthreads();
    }
    int ex = ps[tid] - tsum;
    int o0 = s0 + ex, o1 = o0 + c0, o2 = o1 + c1, o3 = o2 + c2;
    cur[base4] = o0; cur[base4 + 1] = o1; cur[base4 + 2] = o2; cur[base4 + 3] = o3;
    int v = (b << BSH) + base4;
    if (v < N)     { rowptr[v] = o0;     dinv[v] = rsqrtf((float)(c0 + 1)); }
    if (v + 1 < N) { rowptr[v + 1] = o1; dinv[v + 1] = rsqrtf((float)(c1 + 1)); }
    if (v + 2 < N) { rowptr[v + 2] = o2; dinv[v + 2] = rsqrtf((float)(c2 + 1)); }
    if (v + 3 < N) { rowptr[v + 3] = o3; dinv[v + 3] = rsqrtf((float)(c3 + 1)); }
    if (b == nb - 1 && tid == 0) rowptr[N] = E;
    __syncthreads();
    for (int i = s0 + tid; i < s1; i += 256) {
        unsigned w = staging[i];
        int p = atomicAdd(&cur[w >> 18], 1);
        col[p] = (int)(w & 0x3FFFF);
    }
}

// ---- layer-1 dense ----
__global__ void k_l1(const u16* __restrict__ x, const u16* __restrict__ wseg,
                     const float* __restrict__ dinv, int N, u16* __restrict__ y) {
    __shared__ float w[MOLD * HID];
    int tid = threadIdx.x;
    for (int i = tid; i < MOLD * HID; i += blockDim.x) w[i] = bf2f(wseg[i]);
    __syncthreads();
    int v = blockIdx.x * 4 + (tid >> 6);
    int f = tid & 63;
    if (v >= N) return;
    float acc = 0.f;
#pragma unroll
    for (int k = 0; k < MOLD; k++) acc += bf2f(x[v * MOLD + k]) * w[k * HID + f];
    y[v * HID + f] = f2bf(dinv[v] * acc);
}

__device__ __forceinline__ void load_bias(const u16* bseg, int fg, float* breg) {
    uint4 bv = ((const uint4*)bseg)[fg];
    unpack_set(bv, breg);
}

// ---- gather core (round-5 structure + 2-batch load ILP, single accumulator) ----
// h[8] (post-relu) for feats fg*8+j, valid on ALL lanes
__device__ __forceinline__ void gather_node(const u16* __restrict__ y,
                                            const int* __restrict__ rowptr,
                                            const int* __restrict__ col,
                                            float dv, const float* breg,
                                            int v, int eslot, int fg, float* hj) {
    float acc[8];
    const u16* yf = y + fg * 8;   // lane-constant feature offset
    if (eslot == 0) {
        unpack_set(*(const uint4*)(yf + (size_t)v * HID), acc);
    } else {
#pragma unroll
        for (int j = 0; j < 8; j++) acc[j] = 0.f;
    }
    int s = rowptr[v], e = rowptr[v + 1];
    int i = s + eslot;
    // two independent row-loads in flight per iteration, same accumulator
    for (; i + 8 < e; i += 16) {
        int u0 = col[i];
        int u1 = col[i + 8];
        uint4 r0 = *(const uint4*)(yf + (size_t)u0 * HID);
        uint4 r1 = *(const uint4*)(yf + (size_t)u1 * HID);
        unpack_add(r0, acc);
        unpack_add(r1, acc);
    }
    if (i < e) {
        int u = col[i];
        uint4 r = *(const uint4*)(yf + (size_t)u * HID);
        unpack_add(r, acc);
    }
    // butterfly over eslot (lane bits 3,4,5)
#pragma unroll
    for (int j = 0; j < 8; j++) acc[j] += __shfl_xor(acc[j], 8);
#pragma unroll
    for (int j = 0; j < 8; j++) acc[j] += __shfl_xor(acc[j], 16);
#pragma unroll
    for (int j = 0; j < 8; j++) acc[j] += __shfl_xor(acc[j], 32);
#pragma unroll
    for (int j = 0; j < 8; j++) hj[j] = fmaxf(dv * acc[j] + breg[j], 0.f);
}

__device__ __forceinline__ void store_row(u16* __restrict__ h, int v, int fg, const float* hj) {
    uint4 o;
    o.x = (unsigned)f2bf(hj[0]) | ((unsigned)f2bf(hj[1]) << 16);
    o.y = (unsigned)f2bf(hj[2]) | ((unsigned)f2bf(hj[3]) << 16);
    o.z = (unsigned)f2bf(hj[4]) | ((unsigned)f2bf(hj[5]) << 16);
    o.w = (unsigned)f2bf(hj[6]) | ((unsigned)f2bf(hj[7]) << 16);
    ((uint4*)(h + (size_t)v * HID))[fg] = o;
}

// ---- agg layers 1,2 ----
__global__ __launch_bounds__(256, 4) void k_agg(
        const u16* __restrict__ y, const int* __restrict__ rowptr,
        const int* __restrict__ col, const float* __restrict__ dinv,
        const u16* __restrict__ bseg, int N, u16* __restrict__ h) {
    int lane = threadIdx.x & 63;
    int eslot = lane >> 3, fg = lane & 7;
    int wid = (blockIdx.x * blockDim.x + threadIdx.x) >> 6;
    int nw = (gridDim.x * blockDim.x) >> 6;
    float breg[8];
    load_bias(bseg, fg, breg);
    int cpw = (N + nw - 1) / nw;
    int v0 = wid * cpw;
    int v1 = v0 + cpw; if (v1 > N) v1 = N;
    for (int v = v0; v < v1; ++v) {
        float hj[8];
        gather_node(y, rowptr, col, dinv[v], breg, v, eslot, fg, hj);
        if (eslot == 0) store_row(h, v, fg, hj);
    }
}

// ---- agg layer 3 + fused pooling ----
__global__ __launch_bounds__(256, 4) void k_aggpool(
        const u16* __restrict__ y, const int* __restrict__ rowptr,
        const int* __restrict__ col, const float* __restrict__ dinv,
        const u16* __restrict__ bseg, const int* __restrict__ batch, int N,
        float* __restrict__ hsum, int* __restrict__ hmax, int* __restrict__ cnt) {
    int lane = threadIdx.x & 63;
    int eslot = lane >> 3, fg = lane & 7;
    int wid = (blockIdx.x * blockDim.x + threadIdx.x) >> 6;
    int nw = (gridDim.x * blockDim.x) >> 6;
    float breg[8];
    load_bias(bseg, fg, breg);
    int cpw = (N + nw - 1) / nw;
    int v0 = wid * cpw;
    int v1 = v0 + cpw; if (v1 > N) v1 = N;
    int gcur = -1, pcnt = 0;
    float psum[8], pmax[8];
#pragma unroll
    for (int j = 0; j < 8; j++) { psum[j] = 0.f; pmax[j] = 0.f; }
    for (int v = v0; v < v1; ++v) {
        float hj[8];
        gather_node(y, rowptr, col, dinv[v], breg, v, eslot, fg, hj);
        int g = batch[v];
        if (g != gcur) {
            if (gcur >= 0) {
                if (eslot == 0) {
#pragma unroll
                    for (int j = 0; j < 8; j++) {
                        atomicAdd(&hsum[gcur * HID + fg * 8 + j], psum[j]);
                        atomicMax(&hmax[gcur * HID + fg * 8 + j], __float_as_int(pmax[j]));
                    }
                }
                if (lane == 0) atomicAdd(&cnt[gcur], pcnt);
            }
#pragma unroll
            for (int j = 0; j < 8; j++) { psum[j] = 0.f; pmax[j] = 0.f; }
            pcnt = 0;
            gcur = g;
        }
        pcnt++;
#pragma unroll
        for (int j = 0; j < 8; j++) {
            psum[j] += hj[j];
            pmax[j] = fmaxf(pmax[j], hj[j]);
        }
    }
    if (gcur >= 0) {
        if (eslot == 0) {
#pragma unroll
            for (int j = 0; j < 8; j++) {
                atomicAdd(&hsum[gcur * HID + fg * 8 + j], psum[j]);
                atomicMax(&hmax[gcur * HID + fg * 8 + j], __float_as_int(pmax[j]));
            }
        }
        if (lane == 0) atomicAdd(&cnt[gcur], pcnt);
    }
}

// ---- MFMA 64x64 dense ----
__global__ __launch_bounds__(256, 4) void k_mm(
        const u16* __restrict__ h, const u16* __restrict__ W,
        const float* __restrict__ dinv, int N, u16* __restrict__ y) {
    int lane = threadIdx.x & 63;
    int q = lane >> 4, m = lane & 15;
    int wid = (blockIdx.x * blockDim.x + threadIdx.x) >> 6;
    int nw = (gridDim.x * blockDim.x) >> 6;
    short8 bfrag[4][2];
#pragma unroll
    for (int t = 0; t < 4; ++t)
#pragma unroll
        for (int kh = 0; kh < 2; ++kh) {
            short8 bv;
#pragma unroll
            for (int j = 0; j < 8; ++j)
                bv[j] = (short)W[(kh * 32 + q * 8 + j) * HID + t * 16 + m];
            bfrag[t][kh] = bv;
        }
    const float4v zero = {0.f, 0.f, 0.f, 0.f};
    int ntiles = (N + 15) >> 4;
    for (int tile = wid; tile < ntiles; tile += nw) {
        int base = tile * 16;
        int row = base + m;
        short8 a0 = {0, 0, 0, 0, 0, 0, 0, 0}, a1 = a0;
        if (row < N) {
            uint4 r0 = *(const uint4*)(h + (size_t)row * HID + q * 8);
            uint4 r1 = *(const uint4*)(h + (size_t)row * HID + 32 + q * 8);
            a0 = __builtin_bit_cast(short8, r0);
            a1 = __builtin_bit_cast(short8, r1);
        }
        float4v c[4];
#pragma unroll
        for (int t = 0; t < 4; ++t) c[t] = zero;
#pragma unroll
        for (int t = 0; t < 4; ++t) {
            c[t] = __builtin_amdgcn_mfma_f32_16x16x32_bf16(a0, bfrag[t][0], c[t], 0, 0, 0);
            c[t] = __builtin_amdgcn_mfma_f32_16x16x32_bf16(a1, bfrag[t][1], c[t], 0, 0, 0);
        }
#pragma unroll
        for (int r = 0; r < 4; ++r) {
            int node = base + q * 4 + r;
            if (node < N) {
                float dv = dinv[node];
#pragma unroll
                for (int t = 0; t < 4; ++t)
                    y[(size_t)node * HID + t * 16 + m] = f2bf(c[t][r] * dv);
            }
        }
    }
}

// ---- final linear ----
__global__ void k_final(const float* __restrict__ hsum, const int* __restrict__ hmaxi,
                        const int* __restrict__ cnt, const u16* __restrict__ wlseg,
                        const u16* __restrict__ blseg, const int* __restrict__ flag,
                        int G, void* __restrict__ out) {
    __shared__ float w[2 * HID * HID];
    int tid = threadIdx.x;
    for (int i = tid; i < 2 * HID * HID; i += blockDim.x) w[i] = bf2f(wlseg[i]);
    __syncthreads();
    int g = blockIdx.x * 4 + (tid >> 6);
    int f = tid & 63;
    if (g >= G) return;
    float inv = 1.f / fmaxf((float)cnt[g], 1.f);
    float acc = bf2f(blseg[f]);
#pragma unroll 8
    for (int k = 0; k < HID; k++) acc += (hsum[g * HID + k] * inv) * w[k * HID + f];
#pragma unroll 8
    for (int k = 0; k < HID; k++) acc += __int_as_float(hmaxi[g * HID + k]) * w[(HID + k) * HID + f];
    int mode = *flag;
    if (mode) ((float*)out)[g * HID + f] = acc;
    else      ((u16*)out)[g * HID + f] = f2bf(acc);
}

extern "C" void kernel_launch(void* const* d_in, const int* in_sizes, int n_in,
                              void* d_out, int out_size, void* d_ws, size_t ws_size,
                              hipStream_t stream) {
    const void* x  = d_in[0];
    const int*  ei = (const int*)d_in[1];
    const int*  batch = (const int*)d_in[3];

    const int NX = in_sizes[0];
    const int N  = NX / MOLD;
    const int E  = in_sizes[1] / 2;
    const int G  = out_size / HID;
    const int nb = (N + (1 << BSH) - 1) >> BSH;

    char* p = (char*)d_ws;
    auto alloc = [&](size_t bytes) -> char* {
        char* r = p;
        p += (bytes + 255) & ~(size_t)255;
        return r;
    };
    int*   flag    = (int*)alloc(256);
    int*   rowptr  = (int*)alloc((size_t)(N + 1) * 4);
    float* dinv    = (float*)alloc((size_t)N * 4);
    int*   cntmat  = (int*)alloc((size_t)nb * NBLK * 4);
    u16*   wbf     = (u16*)alloc((size_t)17216 * 2);
    int*   colb    = (int*)alloc((size_t)E * 4);
    size_t hb = (size_t)N * HID * 2;
    size_t sb = (size_t)E * 4;
    size_t xb = (size_t)NX * 2;
    size_t ub = hb > sb ? hb : sb; if (xb > ub) ub = xb;
    char* hbuf = alloc(ub);
    unsigned* staging = (unsigned*)hbuf;
    u16*      xbf     = (u16*)hbuf;
    u16*      hbf     = (u16*)hbuf;
    u16*   ybf  = (u16*)alloc((size_t)N * HID * 2);
    float* hsum = (float*)alloc((size_t)G * HID * 4);
    int*   hmax = (int*)alloc((size_t)G * HID * 4);
    int*   cnt  = (int*)alloc((size_t)G * 4);

    hipMemsetAsync(flag, 0, 256, stream);
    hipMemsetAsync(hsum, 0, (size_t)G * HID * 4, stream);
    hipMemsetAsync(hmax, 0, (size_t)G * HID * 4, stream);
    hipMemsetAsync(cnt, 0, (size_t)G * 4, stream);

    k_detect<<<1, 256, 0, stream>>>((const u16*)x, 8192, flag);
    k_cvt_w<<<1, 256, 0, stream>>>(d_in[4], d_in[5], d_in[6], d_in[7],
                                   d_in[8], d_in[9], d_in[10], d_in[11], flag, wbf);

    int chunk = (E + NBLK - 1) / NBLK;
    k_hist<<<NBLK, 256, 0, stream>>>(ei, E, nb, chunk, cntmat);
    k_scanmat<<<1, 1024, 0, stream>>>(cntmat, nb * NBLK);
    k_scatter<<<NBLK, 256, 0, stream>>>(ei, E, nb, chunk, cntmat, staging);
    k_p4<<<nb, 256, 0, stream>>>(staging, cntmat, nb, N, E, colb, rowptr, dinv);

    k_cvt_x<<<(NX + 255) / 256, 256, 0, stream>>>(x, xbf, NX, flag);
    k_l1<<<(N + 3) / 4, 256, 0, stream>>>(xbf, wbf + 0, dinv, N, ybf);

    k_agg<<<2048, 256, 0, stream>>>(ybf, rowptr, colb, dinv, wbf + 576, N, hbf);
    k_mm<<<1024, 256, 0, stream>>>(hbf, wbf + 640, dinv, N, ybf);
    k_agg<<<2048, 256, 0, stream>>>(ybf, rowptr, colb, dinv, wbf + 4736, N, hbf);
    k_mm<<<1024, 256, 0, stream>>>(hbf, wbf + 4800, dinv, N, ybf);
    k_aggpool<<<2048, 256, 0, stream>>>(ybf, rowptr, colb, dinv, wbf + 8896, batch, N,
                                        hsum, hmax, cnt);

    k_final<<<(G + 3) / 4, 256, 0, stream>>>(hsum, hmax, cnt, wbf + 8960, wbf + 17152,
                                             flag, G, d_out);
}

// Round 8
// 677.304 us; speedup vs baseline: 1.2164x; 1.0367x over previous
//
#include <hip/hip_runtime.h>

typedef unsigned short u16;
typedef __attribute__((ext_vector_type(8))) short short8;
typedef __attribute__((ext_vector_type(4))) float float4v;

#define HID 64
#define MOLD 9
#define BSH 10           // bucket covers 1<<BSH = 1024 nodes
#define NBM 256          // max buckets (N <= 262144; src packs in 18 bits)
#define NBLK 256         // partition blocks

__device__ __forceinline__ float bf2f(u16 u) {
    return __uint_as_float(((unsigned)u) << 16);
}
__device__ __forceinline__ u16 f2bf(float f) {
    unsigned x = __float_as_uint(f);
    unsigned r = (x + 0x7FFFu + ((x >> 16) & 1u)) >> 16;  // round-nearest-even
    return (u16)r;
}
__device__ __forceinline__ void unpack_add(uint4 r, float* a) {
    a[0] += __uint_as_float(r.x << 16); a[1] += __uint_as_float(r.x & 0xffff0000u);
    a[2] += __uint_as_float(r.y << 16); a[3] += __uint_as_float(r.y & 0xffff0000u);
    a[4] += __uint_as_float(r.z << 16); a[5] += __uint_as_float(r.z & 0xffff0000u);
    a[6] += __uint_as_float(r.w << 16); a[7] += __uint_as_float(r.w & 0xffff0000u);
}
__device__ __forceinline__ void unpack_set(uint4 r, float* a) {
    a[0] = __uint_as_float(r.x << 16); a[1] = __uint_as_float(r.x & 0xffff0000u);
    a[2] = __uint_as_float(r.y << 16); a[3] = __uint_as_float(r.y & 0xffff0000u);
    a[4] = __uint_as_float(r.z << 16); a[5] = __uint_as_float(r.z & 0xffff0000u);
    a[6] = __uint_as_float(r.w << 16); a[7] = __uint_as_float(r.w & 0xffff0000u);
}

// ---- dtype probe ----
__global__ void k_detect(const u16* __restrict__ p, int n, int* __restrict__ flag) {
    bool bad = false;
    for (int i = threadIdx.x; i < n; i += 256) {
        float v = bf2f(p[i]);
        if (!(v == v) || fabsf(v) > 1000.f) bad = true;
    }
    if (bad) atomicOr(flag, 1);
}

__device__ __forceinline__ void cvt_seg(const void* src, u16* dst, int n, int mode) {
    if (mode) {
        const float* s = (const float*)src;
        for (int i = threadIdx.x; i < n; i += 256) dst[i] = f2bf(s[i]);
    } else {
        const u16* s = (const u16*)src;
        for (int i = threadIdx.x; i < n; i += 256) dst[i] = s[i];
    }
}

__global__ void k_cvt_w(const void* W1, const void* b1, const void* W2, const void* b2,
                        const void* W3, const void* b3, const void* Wl, const void* bl,
                        const int* __restrict__ flag, u16* __restrict__ wbf) {
    int mode = *flag;
    cvt_seg(W1, wbf + 0,     MOLD * HID, mode);
    cvt_seg(b1, wbf + 576,   HID, mode);
    cvt_seg(W2, wbf + 640,   HID * HID, mode);
    cvt_seg(b2, wbf + 4736,  HID, mode);
    cvt_seg(W3, wbf + 4800,  HID * HID, mode);
    cvt_seg(b3, wbf + 8896,  HID, mode);
    cvt_seg(Wl, wbf + 8960,  2 * HID * HID, mode);
    cvt_seg(bl, wbf + 17152, HID, mode);
}

__global__ void k_cvt_x(const void* __restrict__ src, u16* __restrict__ dst, int n,
                        const int* __restrict__ flag) {
    int mode = *flag;
    int i = blockIdx.x * 256 + threadIdx.x;
    if (i >= n) return;
    dst[i] = mode ? f2bf(((const float*)src)[i]) : ((const u16*)src)[i];
}

// ==== atomic-free two-level radix CSR build ====
__global__ __launch_bounds__(256) void k_hist(const int* __restrict__ ei, int E, int nb,
                                              int chunk, int* __restrict__ cntmat) {
    __shared__ int h[NBM];
    int tid = threadIdx.x, k = blockIdx.x;
    for (int i = tid; i < nb; i += 256) h[i] = 0;
    __syncthreads();
    int e0 = k * chunk, e1 = e0 + chunk; if (e1 > E) e1 = E;
    for (int e = e0 + tid; e < e1; e += 256)
        atomicAdd(&h[ei[E + e] >> BSH], 1);
    __syncthreads();
    for (int b = tid; b < nb; b += 256) cntmat[b * NBLK + k] = h[b];
}

__global__ __launch_bounds__(1024) void k_scanmat(int* __restrict__ cntmat, int total) {
    __shared__ int ps[1024];
    int tid = threadIdx.x;
    int chunk = (total + 1023) >> 10;
    int i0 = tid * chunk, i1 = i0 + chunk; if (i1 > total) i1 = total;
    int sum = 0;
    for (int i = i0; i < i1; i++) sum += cntmat[i];
    ps[tid] = sum;
    __syncthreads();
    for (int off = 1; off < 1024; off <<= 1) {
        int t = (tid >= off) ? ps[tid - off] : 0;
        __syncthreads();
        ps[tid] += t;
        __syncthreads();
    }
    int run = ps[tid] - sum;
    for (int i = i0; i < i1; i++) { int c = cntmat[i]; cntmat[i] = run; run += c; }
}

__global__ __launch_bounds__(256) void k_scatter(const int* __restrict__ ei, int E, int nb,
                                                 int chunk, const int* __restrict__ offmat,
                                                 unsigned* __restrict__ staging) {
    __shared__ int cur[NBM];
    int tid = threadIdx.x, k = blockIdx.x;
    for (int b = tid; b < nb; b += 256) cur[b] = offmat[b * NBLK + k];
    __syncthreads();
    int e0 = k * chunk, e1 = e0 + chunk; if (e1 > E) e1 = E;
    for (int e = e0 + tid; e < e1; e += 256) {
        int s = ei[e];
        int d = ei[E + e];
        int b = d >> BSH;
        int p = atomicAdd(&cur[b], 1);
        staging[p] = (unsigned)s | ((unsigned)(d & ((1 << BSH) - 1)) << 18);
    }
}

__global__ __launch_bounds__(256) void k_p4(const unsigned* __restrict__ staging,
                                            const int* __restrict__ offmat, int nb, int N, int E,
                                            int* __restrict__ col, int* __restrict__ rowptr,
                                            float* __restrict__ dinv) {
    __shared__ int cnt[1 << BSH];
    __shared__ int cur[1 << BSH];
    __shared__ int ps[256];
    int b = blockIdx.x, tid = threadIdx.x;
    int s0 = offmat[b * NBLK];
    int s1 = (b == nb - 1) ? E : offmat[(b + 1) * NBLK];
    for (int i = tid; i < (1 << BSH); i += 256) cnt[i] = 0;
    __syncthreads();
    for (int i = s0 + tid; i < s1; i += 256)
        atomicAdd(&cnt[staging[i] >> 18], 1);
    __syncthreads();
    int base4 = tid * 4;
    int c0 = cnt[base4], c1 = cnt[base4 + 1], c2 = cnt[base4 + 2], c3 = cnt[base4 + 3];
    int tsum = c0 + c1 + c2 + c3;
    ps[tid] = tsum;
    __syncthreads();
    for (int off = 1; off < 256; off <<= 1) {
        int t = (tid >= off) ? ps[tid - off] : 0;
        __syncthreads();
        ps[tid] += t;
        __syncthreads();
    }
    int ex = ps[tid] - tsum;
    int o0 = s0 + ex, o1 = o0 + c0, o2 = o1 + c1, o3 = o2 + c2;
    cur[base4] = o0; cur[base4 + 1] = o1; cur[base4 + 2] = o2; cur[base4 + 3] = o3;
    int v = (b << BSH) + base4;
    if (v < N)     { rowptr[v] = o0;     dinv[v] = rsqrtf((float)(c0 + 1)); }
    if (v + 1 < N) { rowptr[v + 1] = o1; dinv[v + 1] = rsqrtf((float)(c1 + 1)); }
    if (v + 2 < N) { rowptr[v + 2] = o2; dinv[v + 2] = rsqrtf((float)(c2 + 1)); }
    if (v + 3 < N) { rowptr[v + 3] = o3; dinv[v + 3] = rsqrtf((float)(c3 + 1)); }
    if (b == nb - 1 && tid == 0) rowptr[N] = E;
    __syncthreads();
    for (int i = s0 + tid; i < s1; i += 256) {
        unsigned w = staging[i];
        int p = atomicAdd(&cur[w >> 18], 1);
        col[p] = (int)(w & 0x3FFFF);
    }
}

// ---- layer-1 dense ----
__global__ void k_l1(const u16* __restrict__ x, const u16* __restrict__ wseg,
                     const float* __restrict__ dinv, int N, u16* __restrict__ y) {
    __shared__ float w[MOLD * HID];
    int tid = threadIdx.x;
    for (int i = tid; i < MOLD * HID; i += blockDim.x) w[i] = bf2f(wseg[i]);
    __syncthreads();
    int v = blockIdx.x * 4 + (tid >> 6);
    int f = tid & 63;
    if (v >= N) return;
    float acc = 0.f;
#pragma unroll
    for (int k = 0; k < MOLD; k++) acc += bf2f(x[v * MOLD + k]) * w[k * HID + f];
    y[v * HID + f] = f2bf(dinv[v] * acc);
}

// ---- gather core: round-5 edge loop + halving reduction (14 shfl, 1 value/lane) ----
// Returns post-relu value of feature idx = fg*8 + bitrev3(eslot) for node v.
__device__ __forceinline__ float gather_node_one(const u16* __restrict__ y,
                                                 const int* __restrict__ rowptr,
                                                 const int* __restrict__ col,
                                                 float dv, float bias,
                                                 int v, int eslot, int fg) {
    float acc[8];
    const u16* yf = y + fg * 8;   // lane-constant feature offset
    if (eslot == 0) {
        unpack_set(*(const uint4*)(yf + (size_t)v * HID), acc);
    } else {
#pragma unroll
        for (int j = 0; j < 8; j++) acc[j] = 0.f;
    }
    int e = rowptr[v + 1];
    for (int i = rowptr[v] + eslot; i < e; i += 8) {
        int u = col[i];
        uint4 r = *(const uint4*)(yf + (size_t)u * HID);
        unpack_add(r, acc);
    }
    // halving butterfly over eslot bits (lane bits 3,4,5): 8+4+2 = 14 shfl
    bool e0 = (eslot & 1) != 0, e1 = (eslot & 2) != 0, e2 = (eslot & 4) != 0;
    float s[8];
#pragma unroll
    for (int j = 0; j < 8; j++) s[j] = acc[j] + __shfl_xor(acc[j], 8);
    float b4[4];
#pragma unroll
    for (int k = 0; k < 4; k++) b4[k] = e0 ? s[k + 4] : s[k];
#pragma unroll
    for (int k = 0; k < 4; k++) b4[k] += __shfl_xor(b4[k], 16);
    float c2[2];
    c2[0] = e1 ? b4[2] : b4[0];
    c2[1] = e1 ? b4[3] : b4[1];
    c2[0] += __shfl_xor(c2[0], 32);
    c2[1] += __shfl_xor(c2[1], 32);
    float val = e2 ? c2[1] : c2[0];
    return fmaxf(dv * val + bias, 0.f);
}

// ---- agg layers 1,2: round-robin node assignment, all-lane 2B store ----
__global__ __launch_bounds__(256, 4) void k_agg(
        const u16* __restrict__ y, const int* __restrict__ rowptr,
        const int* __restrict__ col, const float* __restrict__ dinv,
        const u16* __restrict__ bseg, int N, u16* __restrict__ h) {
    int lane = threadIdx.x & 63;
    int eslot = lane >> 3, fg = lane & 7;
    int idx = fg * 8 + ((eslot & 1) << 2) + (eslot & 2) + ((eslot >> 2) & 1);
    float bias = bf2f(bseg[idx]);
    int wid = (blockIdx.x * blockDim.x + threadIdx.x) >> 6;
    int nw = (gridDim.x * blockDim.x) >> 6;
    for (int v = wid; v < N; v += nw) {
        float hv = gather_node_one(y, rowptr, col, dinv[v], bias, v, eslot, fg);
        h[(size_t)v * HID + idx] = f2bf(hv);
    }
}

// ---- agg layer 3 + fused pooling (chunked for batch-run locality) ----
__global__ __launch_bounds__(256, 4) void k_aggpool(
        const u16* __restrict__ y, const int* __restrict__ rowptr,
        const int* __restrict__ col, const float* __restrict__ dinv,
        const u16* __restrict__ bseg, const int* __restrict__ batch, int N,
        float* __restrict__ hsum, int* __restrict__ hmax, int* __restrict__ cnt) {
    int lane = threadIdx.x & 63;
    int eslot = lane >> 3, fg = lane & 7;
    int idx = fg * 8 + ((eslot & 1) << 2) + (eslot & 2) + ((eslot >> 2) & 1);
    float bias = bf2f(bseg[idx]);
    int wid = (blockIdx.x * blockDim.x + threadIdx.x) >> 6;
    int nw = (gridDim.x * blockDim.x) >> 6;
    int cpw = (N + nw - 1) / nw;
    int v0 = wid * cpw;
    int v1 = v0 + cpw; if (v1 > N) v1 = N;
    int gcur = -1, pcnt = 0;
    float psum = 0.f, pmax = 0.f;
    for (int v = v0; v < v1; ++v) {
        float hv = gather_node_one(y, rowptr, col, dinv[v], bias, v, eslot, fg);
        int g = batch[v];
        if (g != gcur) {
            if (gcur >= 0) {
                atomicAdd(&hsum[gcur * HID + idx], psum);
                atomicMax(&hmax[gcur * HID + idx], __float_as_int(pmax));
                if (lane == 0) atomicAdd(&cnt[gcur], pcnt);
            }
            psum = 0.f; pmax = 0.f; pcnt = 0;
            gcur = g;
        }
        pcnt++;
        psum += hv;
        pmax = fmaxf(pmax, hv);
    }
    if (gcur >= 0) {
        atomicAdd(&hsum[gcur * HID + idx], psum);
        atomicMax(&hmax[gcur * HID + idx], __float_as_int(pmax));
        if (lane == 0) atomicAdd(&cnt[gcur], pcnt);
    }
}

// ---- MFMA 64x64 dense ----
__global__ __launch_bounds__(256, 4) void k_mm(
        const u16* __restrict__ h, const u16* __restrict__ W,
        const float* __restrict__ dinv, int N, u16* __restrict__ y) {
    int lane = threadIdx.x & 63;
    int q = lane >> 4, m = lane & 15;
    int wid = (blockIdx.x * blockDim.x + threadIdx.x) >> 6;
    int nw = (gridDim.x * blockDim.x) >> 6;
    short8 bfrag[4][2];
#pragma unroll
    for (int t = 0; t < 4; ++t)
#pragma unroll
        for (int kh = 0; kh < 2; ++kh) {
            short8 bv;
#pragma unroll
            for (int j = 0; j < 8; ++j)
                bv[j] = (short)W[(kh * 32 + q * 8 + j) * HID + t * 16 + m];
            bfrag[t][kh] = bv;
        }
    const float4v zero = {0.f, 0.f, 0.f, 0.f};
    int ntiles = (N + 15) >> 4;
    for (int tile = wid; tile < ntiles; tile += nw) {
        int base = tile * 16;
        int row = base + m;
        short8 a0 = {0, 0, 0, 0, 0, 0, 0, 0}, a1 = a0;
        if (row < N) {
            uint4 r0 = *(const uint4*)(h + (size_t)row * HID + q * 8);
            uint4 r1 = *(const uint4*)(h + (size_t)row * HID + 32 + q * 8);
            a0 = __builtin_bit_cast(short8, r0);
            a1 = __builtin_bit_cast(short8, r1);
        }
        float4v c[4];
#pragma unroll
        for (int t = 0; t < 4; ++t) c[t] = zero;
#pragma unroll
        for (int t = 0; t < 4; ++t) {
            c[t] = __builtin_amdgcn_mfma_f32_16x16x32_bf16(a0, bfrag[t][0], c[t], 0, 0, 0);
            c[t] = __builtin_amdgcn_mfma_f32_16x16x32_bf16(a1, bfrag[t][1], c[t], 0, 0, 0);
        }
#pragma unroll
        for (int r = 0; r < 4; ++r) {
            int node = base + q * 4 + r;
            if (node < N) {
                float dv = dinv[node];
#pragma unroll
                for (int t = 0; t < 4; ++t)
                    y[(size_t)node * HID + t * 16 + m] = f2bf(c[t][r] * dv);
            }
        }
    }
}

// ---- final linear ----
__global__ void k_final(const float* __restrict__ hsum, const int* __restrict__ hmaxi,
                        const int* __restrict__ cnt, const u16* __restrict__ wlseg,
                        const u16* __restrict__ blseg, const int* __restrict__ flag,
                        int G, void* __restrict__ out) {
    __shared__ float w[2 * HID * HID];
    int tid = threadIdx.x;
    for (int i = tid; i < 2 * HID * HID; i += blockDim.x) w[i] = bf2f(wlseg[i]);
    __syncthreads();
    int g = blockIdx.x * 4 + (tid >> 6);
    int f = tid & 63;
    if (g >= G) return;
    float inv = 1.f / fmaxf((float)cnt[g], 1.f);
    float acc = bf2f(blseg[f]);
#pragma unroll 8
    for (int k = 0; k < HID; k++) acc += (hsum[g * HID + k] * inv) * w[k * HID + f];
#pragma unroll 8
    for (int k = 0; k < HID; k++) acc += __int_as_float(hmaxi[g * HID + k]) * w[(HID + k) * HID + f];
    int mode = *flag;
    if (mode) ((float*)out)[g * HID + f] = acc;
    else      ((u16*)out)[g * HID + f] = f2bf(acc);
}

extern "C" void kernel_launch(void* const* d_in, const int* in_sizes, int n_in,
                              void* d_out, int out_size, void* d_ws, size_t ws_size,
                              hipStream_t stream) {
    const void* x  = d_in[0];
    const int*  ei = (const int*)d_in[1];
    const int*  batch = (const int*)d_in[3];

    const int NX = in_sizes[0];
    const int N  = NX / MOLD;
    const int E  = in_sizes[1] / 2;
    const int G  = out_size / HID;
    const int nb = (N + (1 << BSH) - 1) >> BSH;

    char* p = (char*)d_ws;
    auto alloc = [&](size_t bytes) -> char* {
        char* r = p;
        p += (bytes + 255) & ~(size_t)255;
        return r;
    };
    int*   flag    = (int*)alloc(256);
    int*   rowptr  = (int*)alloc((size_t)(N + 1) * 4);
    float* dinv    = (float*)alloc((size_t)N * 4);
    int*   cntmat  = (int*)alloc((size_t)nb * NBLK * 4);
    u16*   wbf     = (u16*)alloc((size_t)17216 * 2);
    int*   colb    = (int*)alloc((size_t)E * 4);
    size_t hb = (size_t)N * HID * 2;
    size_t sb = (size_t)E * 4;
    size_t xb = (size_t)NX * 2;
    size_t ub = hb > sb ? hb : sb; if (xb > ub) ub = xb;
    char* hbuf = alloc(ub);
    unsigned* staging = (unsigned*)hbuf;
    u16*      xbf     = (u16*)hbuf;
    u16*      hbf     = (u16*)hbuf;
    u16*   ybf  = (u16*)alloc((size_t)N * HID * 2);
    float* hsum = (float*)alloc((size_t)G * HID * 4);
    int*   hmax = (int*)alloc((size_t)G * HID * 4);
    int*   cnt  = (int*)alloc((size_t)G * 4);

    hipMemsetAsync(flag, 0, 256, stream);
    hipMemsetAsync(hsum, 0, (size_t)G * HID * 4, stream);
    hipMemsetAsync(hmax, 0, (size_t)G * HID * 4, stream);
    hipMemsetAsync(cnt, 0, (size_t)G * 4, stream);

    k_detect<<<1, 256, 0, stream>>>((const u16*)x, 8192, flag);
    k_cvt_w<<<1, 256, 0, stream>>>(d_in[4], d_in[5], d_in[6], d_in[7],
                                   d_in[8], d_in[9], d_in[10], d_in[11], flag, wbf);

    int chunk = (E + NBLK - 1) / NBLK;
    k_hist<<<NBLK, 256, 0, stream>>>(ei, E, nb, chunk, cntmat);
    k_scanmat<<<1, 1024, 0, stream>>>(cntmat, nb * NBLK);
    k_scatter<<<NBLK, 256, 0, stream>>>(ei, E, nb, chunk, cntmat, staging);
    k_p4<<<nb, 256, 0, stream>>>(staging, cntmat, nb, N, E, colb, rowptr, dinv);

    k_cvt_x<<<(NX + 255) / 256, 256, 0, stream>>>(x, xbf, NX, flag);
    k_l1<<<(N + 3) / 4, 256, 0, stream>>>(xbf, wbf + 0, dinv, N, ybf);

    k_agg<<<2048, 256, 0, stream>>>(ybf, rowptr, colb, dinv, wbf + 576, N, hbf);
    k_mm<<<1024, 256, 0, stream>>>(hbf, wbf + 640, dinv, N, ybf);
    k_agg<<<2048, 256, 0, stream>>>(ybf, rowptr, colb, dinv, wbf + 4736, N, hbf);
    k_mm<<<1024, 256, 0, stream>>>(hbf, wbf + 4800, dinv, N, ybf);
    k_aggpool<<<2048, 256, 0, stream>>>(ybf, rowptr, colb, dinv, wbf + 8896, batch, N,
                                        hsum, hmax, cnt);

    k_final<<<(G + 3) / 4, 256, 0, stream>>>(hsum, hmax, cnt, wbf + 8960, wbf + 17152,
                                             flag, G, d_out);
}